// Round 12
// baseline (286.210 us; speedup 1.0000x reference)
//
#include <hip/hip_runtime.h>
#include <hip/hip_bf16.h>

#define N_ATOMS 30000
#define M_NBR   12

typedef __bf16 bf16x8 __attribute__((ext_vector_type(8)));
typedef float  f32x4  __attribute__((ext_vector_type(4)));

__device__ __forceinline__ unsigned pkbf(float a, float b) {
    union { __bf16 h[2]; unsigned u; } r;
    r.h[0] = (__bf16)a; r.h[1] = (__bf16)b;
    return r.u;
}
__device__ __forceinline__ unsigned short f2bf(float f) {
    union { __bf16 h; unsigned short s; } r; r.h = (__bf16)f; return r.s;
}
__device__ __forceinline__ float bflo(unsigned u) { union { unsigned x; float f; } v; v.x = u << 16;          return v.f; }
__device__ __forceinline__ float bfhi(unsigned u) { union { unsigned x; float f; } v; v.x = u & 0xffff0000u;  return v.f; }

__device__ __forceinline__ float fexp2(float x) { return __builtin_amdgcn_exp2f(x); }
__device__ __forceinline__ float flog2(float x) { return __builtin_amdgcn_logf(x); }

__device__ __forceinline__ float rowsum16(float x) {
    union { float f; int i; } a, b;
    a.f = x;
    b.i = __builtin_amdgcn_update_dpp(0, a.i, 0x121, 0xF, 0xF, true); a.f += b.f; // row_ror:1
    b.i = __builtin_amdgcn_update_dpp(0, a.i, 0x122, 0xF, 0xF, true); a.f += b.f; // row_ror:2
    b.i = __builtin_amdgcn_update_dpp(0, a.i, 0x124, 0xF, 0xF, true); a.f += b.f; // row_ror:4
    b.i = __builtin_amdgcn_update_dpp(0, a.i, 0x128, 0xF, 0xF, true); a.f += b.f; // row_ror:8
    return a.f;
}

// packed per-row address for z-column c (0..511): [band:8][l15:16][slot:4]
__device__ __forceinline__ int packAddr8(int c) {
    int cc = c & 255;
    int slot = ((cc >> 4) & 1) + ((c >> 8) << 1);
    return (cc >> 5) * 64 + (cc & 15) * 4 + slot;
}

// ---------------- Kernel 0: pack fc_w into bf16 fragment-order tables ----------
__global__ void pack_weights(const float* __restrict__ fc_w,
                             unsigned short* __restrict__ Wp1,
                             unsigned short* __restrict__ Wp3) {
    int idx = blockIdx.x * 256 + threadIdx.x;
    const int n1 = 32 * 1024 * 8;
    if (idx < n1) {
        int j = idx & 7, n = (idx >> 3) & 1023, g = idx >> 13;
        float v = (n < 512) ? fc_w[n * 640 + g * 8 + j]
                            : fc_w[(n - 512) * 640 + 256 + g * 8 + j];
        Wp1[idx] = f2bf(v);
    } else {
        int k = idx - n1;
        if (k < 16 * 512 * 8) {
            int j = k & 7, n = (k >> 3) & 511, g = k >> 12;
            Wp3[k] = f2bf(fc_w[n * 640 + 512 + g * 8 + j]);
        }
    }
}

// ---------------- Kernel 1: P1 = W1*atom + b, P2 = W2*atom, stored PACKED (bf16) ---
__global__ __launch_bounds__(512, 2) void gemm_p(
    const float* __restrict__ atom, const float* __restrict__ fc_b,
    const unsigned short* __restrict__ Wp1, unsigned short* __restrict__ P)
{
    __shared__ unsigned short sA[128 * 256];
    const int tid = threadIdx.x;
    const int r0 = blockIdx.x * 128;
    const int cb = blockIdx.y;

    #pragma unroll
    for (int s = 0; s < 8; ++s) {
        int G = tid + s * 512;
        int row = G >> 5, gc = G & 31;
        int grow = r0 + row;
        uint4 pk;
        if (grow < N_ATOMS) {
            const float4* src = reinterpret_cast<const float4*>(atom + (size_t)grow * 256 + gc * 8);
            float4 v0 = src[0], v1 = src[1];
            pk.x = pkbf(v0.x, v0.y); pk.y = pkbf(v0.z, v0.w);
            pk.z = pkbf(v1.x, v1.y); pk.w = pkbf(v1.z, v1.w);
        } else {
            pk = make_uint4(0u, 0u, 0u, 0u);
        }
        *reinterpret_cast<uint4*>(&sA[row * 256 + ((gc ^ (row & 7)) << 3)]) = pk;
    }
    __syncthreads();

    const int lane = tid & 63, wave = tid >> 6;
    const int wr = wave >> 2, wcc = wave & 3;
    const int l15 = lane & 15, l16 = lane >> 4;

    f32x4 acc[4][8];
    #pragma unroll
    for (int mt = 0; mt < 4; ++mt)
        #pragma unroll
        for (int nt = 0; nt < 8; ++nt) acc[mt][nt] = f32x4{0.f, 0.f, 0.f, 0.f};

    #pragma unroll
    for (int ks = 0; ks < 8; ++ks) {
        bf16x8 af[4];
        #pragma unroll
        for (int mt = 0; mt < 4; ++mt) {
            int row = wr * 64 + mt * 16 + l15;
            int g = ks * 4 + l16;
            af[mt] = *reinterpret_cast<const bf16x8*>(&sA[row * 256 + ((g ^ (row & 7)) << 3)]);
        }
        bf16x8 bfr[8];
        #pragma unroll
        for (int nt = 0; nt < 8; ++nt) {
            int col = cb * 512 + wcc * 128 + nt * 16 + l15;
            bfr[nt] = *reinterpret_cast<const bf16x8*>(&Wp1[((size_t)(ks * 4 + l16) * 1024 + col) * 8]);
        }
        #pragma unroll
        for (int mt = 0; mt < 4; ++mt)
            #pragma unroll
            for (int nt = 0; nt < 8; ++nt)
                acc[mt][nt] = __builtin_amdgcn_mfma_f32_16x16x32_bf16(af[mt], bfr[nt], acc[mt][nt], 0, 0, 0);
    }

    #pragma unroll
    for (int np = 0; np < 4; ++np) {
        int zc0 = wcc * 128 + np * 32 + l15;
        float b0 = (cb == 0) ? fc_b[zc0] : 0.f;
        float b1 = (cb == 0) ? fc_b[zc0 + 16] : 0.f;
        int pa = cb * 512 + packAddr8(zc0);
        #pragma unroll
        for (int mt = 0; mt < 4; ++mt) {
            #pragma unroll
            for (int j = 0; j < 4; ++j) {
                int row = r0 + wr * 64 + mt * 16 + l16 * 4 + j;
                if (row < N_ATOMS)
                    *reinterpret_cast<unsigned*>(&P[(size_t)row * 1024 + pa]) =
                        pkbf(acc[mt][2 * np][j] + b0, acc[mt][2 * np + 1][j] + b1);
            }
        }
    }
}

// ================= Kernel 2 helpers =================
__device__ __forceinline__ void bondLoad(const float* __restrict__ bond, int i0, int tid, float4 bv[3]) {
    #pragma unroll
    for (int s = 0; s < 3; ++s) {
        int g = tid + s * 512;                    // 1536 8B-out granules, exact
        int row = g >> 5, gc = g & 31;
        bv[s] = *reinterpret_cast<const float4*>(bond + (size_t)(i0 * 12 + row) * 128 + gc * 4);
    }
}
__device__ __forceinline__ void bondWrite(const float4 bv[3], int tid, unsigned short* sAbuf) {
    #pragma unroll
    for (int s = 0; s < 3; ++s) {
        int g = tid + s * 512;
        int row = g >> 5, gc = g & 31;
        uint2 pk;
        pk.x = pkbf(bv[s].x, bv[s].y); pk.y = pkbf(bv[s].z, bv[s].w);
        int elem = (((gc >> 1) ^ (row & 7)) << 3) + ((gc & 1) << 2);
        *reinterpret_cast<uint2*>(&sAbuf[row * 128 + elem]) = pk;
    }
}
__device__ __forceinline__ void loadP(const char* __restrict__ Pb, const int* __restrict__ nbr,
                                      int i0, int l16, unsigned cOff, uint2 p2q[12], uint2 p1q[3]) {
    int4 nbq0 = *reinterpret_cast<const int4*>(&nbr[i0 * 12 +      l16 * 4]);
    int4 nbq1 = *reinterpret_cast<const int4*>(&nbr[i0 * 12 + 16 + l16 * 4]);
    int4 nbq2 = *reinterpret_cast<const int4*>(&nbr[i0 * 12 + 32 + l16 * 4]);
    const int* n0 = reinterpret_cast<const int*>(&nbq0);
    const int* n1 = reinterpret_cast<const int*>(&nbq1);
    const int* n2 = reinterpret_cast<const int*>(&nbq2);
    #pragma unroll
    for (int j = 0; j < 4; ++j) {
        p2q[j]     = *reinterpret_cast<const uint2*>(Pb + ((unsigned)n0[j] * 2048u + 1024u + cOff));
        p2q[4 + j] = *reinterpret_cast<const uint2*>(Pb + ((unsigned)n1[j] * 2048u + 1024u + cOff));
        p2q[8 + j] = *reinterpret_cast<const uint2*>(Pb + ((unsigned)n2[j] * 2048u + 1024u + cOff));
    }
    #pragma unroll
    for (int mt = 0; mt < 3; ++mt) {
        unsigned li = (unsigned)((mt * 16 + l16 * 4) / 12);
        p1q[mt] = *reinterpret_cast<const uint2*>(Pb + (((unsigned)i0 + li) * 2048u + cOff));
    }
}
__device__ __forceinline__ void accInit(const uint2 p2q[12], const uint2 p1q[3], f32x4 acc[3][4]) {
    #pragma unroll
    for (int mt = 0; mt < 3; ++mt) {
        uint2 c1 = p1q[mt];
        float p1v[4] = { bflo(c1.x), bfhi(c1.x), bflo(c1.y), bfhi(c1.y) };
        #pragma unroll
        for (int j = 0; j < 4; ++j) {
            uint2 c2 = p2q[mt * 4 + j];
            acc[mt][0][j] = p1v[0] + bflo(c2.x);
            acc[mt][1][j] = p1v[1] + bfhi(c2.x);
            acc[mt][2][j] = p1v[2] + bflo(c2.y);
            acc[mt][3][j] = p1v[3] + bfhi(c2.y);
        }
    }
}
__device__ __forceinline__ void gemmTile(const unsigned short* __restrict__ sAbuf,
                                         const unsigned short* __restrict__ Wp3,
                                         int l15, int l16, int wc, f32x4 acc[3][4]) {
    #pragma unroll
    for (int ks = 0; ks < 4; ++ks) {
        #pragma unroll
        for (int p = 0; p < 2; ++p) {
            bf16x8 b0 = *reinterpret_cast<const bf16x8*>(
                &Wp3[((size_t)(ks * 4 + l16) * 512 + p * 256 + wc * 32 + l15) * 8]);
            bf16x8 b1 = *reinterpret_cast<const bf16x8*>(
                &Wp3[((size_t)(ks * 4 + l16) * 512 + p * 256 + wc * 32 + 16 + l15) * 8]);
            #pragma unroll
            for (int mt = 0; mt < 3; ++mt) {
                int row = mt * 16 + l15;
                bf16x8 af = *reinterpret_cast<const bf16x8*>(
                    &sAbuf[row * 128 + (((ks * 4 + l16) ^ (row & 7)) << 3)]);
                acc[mt][2 * p]     = __builtin_amdgcn_mfma_f32_16x16x32_bf16(af, b0, acc[mt][2 * p], 0, 0, 0);
                acc[mt][2 * p + 1] = __builtin_amdgcn_mfma_f32_16x16x32_bf16(af, b1, acc[mt][2 * p + 1], 0, 0, 0);
            }
        }
    }
}
__device__ __forceinline__ void pass1Stats(const f32x4 acc[3][4], float (*sRed)[48][9],
                                           int l16, int l15, int wc) {
    #pragma unroll
    for (int mt = 0; mt < 3; ++mt) {
        #pragma unroll
        for (int j = 0; j < 4; ++j) {
            const int row = mt * 16 + l16 * 4 + j;
            float z0 = acc[mt][0][j], z1 = acc[mt][1][j];
            float z2 = acc[mt][2][j], z3 = acc[mt][3][j];
            float s = (z0 + z1) + (z2 + z3);
            float q = fmaf(z0, z0, fmaf(z1, z1, fmaf(z2, z2, z3 * z3)));
            s = rowsum16(s);
            q = rowsum16(q);
            if (l15 == 0) { sRed[0][row][wc] = s; sRed[1][row][wc] = q; }
        }
    }
}
__device__ __forceinline__ void miniReduce(int tid, float (*sRed)[48][9], float2* sStat, float L2E) {
    if (tid < 48) {
        float s4 = 0.f, q4 = 0.f;
        #pragma unroll
        for (int w = 0; w < 8; ++w) { s4 += sRed[0][tid][w]; q4 += sRed[1][tid][w]; }
        float mu = s4 * (1.f / 512.f);
        float var = q4 * (1.f / 512.f) - mu * mu;
        float rs = __builtin_amdgcn_rsqf(var + 1e-5f) * L2E;
        sStat[tid] = make_float2(rs, mu * rs);
    }
}
__device__ __forceinline__ void pass2(const f32x4 acc[3][4], const float2* sStat,
                                      const float g1[2], const float gC[2],
                                      const float l2b1[2], const float l2bC[2],
                                      float (*sObuf)[256], int l16, int l15, int wc) {
    #pragma unroll
    for (int mt = 0; mt < 3; ++mt) {
        const int li = (mt * 16 + l16 * 4) / 12;
        float2 st[4];
        #pragma unroll
        for (int j = 0; j < 4; ++j) st[j] = sStat[mt * 16 + l16 * 4 + j];
        #pragma unroll
        for (int nt = 0; nt < 2; ++nt) {
            float tq = 0.f;
            #pragma unroll
            for (int j = 0; j < 4; ++j) {
                float ug = fmaf(fmaf(acc[mt][nt][j],     st[j].x, -st[j].y), g1[nt], l2b1[nt]);
                float uc = fmaf(fmaf(acc[mt][nt + 2][j], st[j].x, -st[j].y), gC[nt], l2bC[nt]);
                float gt  = __builtin_amdgcn_rcpf(1.f + fexp2(-ug));
                float sp2 = flog2(1.f + fexp2(uc));
                tq = fmaf(gt, sp2, tq);
            }
            atomicAdd(&sObuf[li][wc * 32 + nt * 16 + l15], tq);
        }
    }
}
__device__ __forceinline__ void ln2Out(const float (*sObuf)[256], int i0, int wc, int lane,
                                       const float* __restrict__ atom,
                                       const float* __restrict__ ln2_g, const float* __restrict__ ln2_b,
                                       float* __restrict__ out) {
    if (wc < 4) {
        const int gi = i0 + wc;
        float v[4]; float s = 0.f, q = 0.f;
        #pragma unroll
        for (int qd = 0; qd < 4; ++qd) {
            v[qd] = sObuf[wc][lane + qd * 64];
            s += v[qd]; q = fmaf(v[qd], v[qd], q);
        }
        #pragma unroll
        for (int msk = 1; msk <= 32; msk <<= 1) {
            s += __shfl_xor(s, msk, 64);
            q += __shfl_xor(q, msk, 64);
        }
        float mu = s * (1.f / 256.f);
        float var = q * (1.f / 256.f) - mu * mu;
        float rstd = __builtin_amdgcn_rsqf(var + 1e-5f);
        #pragma unroll
        for (int qd = 0; qd < 4; ++qd) {
            int a = lane + qd * 64;
            out[(size_t)gi * 256 + a] = atom[(size_t)gi * 256 + a]
                                      + (v[qd] - mu) * rstd * ln2_g[a] + ln2_b[a];
        }
    }
}

// ---------------- Kernel 2: two software-pipelined tiles (8 atoms) per block ----------------
__global__ __launch_bounds__(512, 4) void fused_conv(
    const float* __restrict__ atom, const float* __restrict__ bond,
    const int* __restrict__ nbr, const unsigned short* __restrict__ P,
    const unsigned short* __restrict__ Wp3,
    const float* __restrict__ ln1_g, const float* __restrict__ ln1_b,
    const float* __restrict__ ln2_g, const float* __restrict__ ln2_b,
    float* __restrict__ out)
{
    __shared__ unsigned short sA[2][48 * 128];   // 24KB double-buffered bond tiles
    __shared__ float sRed[2][48][9];
    __shared__ float2 sStat[48];
    __shared__ float sO[2][4][256];              // 8KB double-buffered mean accumulators

    const int tid = threadIdx.x;
    const int i00 = blockIdx.x * 8;              // 3750 blocks, 2 tiles of 4 atoms each
    const int i01 = i00 + 4;
    const int lane = tid & 63, wc = tid >> 6;
    const int l15 = lane & 15, l16 = lane >> 4;
    const float L2E = 1.4426950408889634f;
    const char* Pb = reinterpret_cast<const char*>(P);
    const unsigned cOff = (unsigned)(wc * 128 + l15 * 8);

    {   // zero both sO buffers
        float* so = &sO[0][0][0];
        so[tid] = 0.f; so[tid + 512] = 0.f; so[tid + 1024] = 0.f; so[tid + 1536] = 0.f;
    }

    // ---- tile0 prologue ----
    float4 bv[3];
    bondLoad(bond, i00, tid, bv);                // HBM, longest latency: issue first
    uint2 p2q[12], p1q[3];
    loadP(Pb, nbr, i00, l16, cOff, p2q, p1q);    // nbr -> gathers, in flight with bond
    bondWrite(bv, tid, sA[0]);                   // waits on bond only
    f32x4 acc[3][4];
    accInit(p2q, p1q, acc);                      // waits gathers; p2q/p1q die here
    __syncthreads();                             // B1: sA[0] ready
    gemmTile(sA[0], Wp3, l15, l16, wc, acc);

    // ---- tile1 prologue: issue now, hide under tile0 epilogue ----
    uint2 P2b[12], P1b[3];
    loadP(Pb, nbr, i01, l16, cOff, P2b, P1b);
    float4 bvb[3];
    bondLoad(bond, i01, tid, bvb);

    // ---- tile0 epilogue ----
    pass1Stats(acc, sRed, l16, l15, wc);
    bondWrite(bvb, tid, sA[1]);                  // waits bond(t1); bvb dies
    float g1[2], gC[2], l2b1[2], l2bC[2];        // LN1 params: shared by both tiles
    #pragma unroll
    for (int nt = 0; nt < 2; ++nt) {
        int a = wc * 32 + nt * 16 + l15;
        g1[nt] = ln1_g[a];       l2b1[nt] = ln1_b[a] * L2E;
        gC[nt] = ln1_g[256 + a]; l2bC[nt] = ln1_b[256 + a] * L2E;
    }
    __syncthreads();                             // B2: sRed(t0) + sA[1] writes done
    miniReduce(tid, sRed, sStat, L2E);
    __syncthreads();                             // B3
    pass2(acc, sStat, g1, gC, l2b1, l2bC, sO[0], l16, l15, wc);
    __syncthreads();                             // B4: sO[0] ready
    ln2Out(sO[0], i00, wc, lane, atom, ln2_g, ln2_b, out);   // waves 0-3; 4-7 fall through

    // ---- tile1 compute ----
    accInit(P2b, P1b, acc);                      // P2b/P1b die here
    gemmTile(sA[1], Wp3, l15, l16, wc, acc);
    pass1Stats(acc, sRed, l16, l15, wc);
    __syncthreads();                             // B5
    miniReduce(tid, sRed, sStat, L2E);
    __syncthreads();                             // B6
    pass2(acc, sStat, g1, gC, l2b1, l2bC, sO[1], l16, l15, wc);
    __syncthreads();                             // B7
    ln2Out(sO[1], i01, wc, lane, atom, ln2_g, ln2_b, out);
}

extern "C" void kernel_launch(void* const* d_in, const int* in_sizes, int n_in,
                              void* d_out, int out_size, void* d_ws, size_t ws_size,
                              hipStream_t stream) {
    const float* atom  = (const float*)d_in[0];
    const float* bond  = (const float*)d_in[1];
    const float* fc_w  = (const float*)d_in[2];
    const float* fc_b  = (const float*)d_in[3];
    const float* ln1_g = (const float*)d_in[4];
    const float* ln1_b = (const float*)d_in[5];
    const float* ln2_g = (const float*)d_in[6];
    const float* ln2_b = (const float*)d_in[7];
    const int*   nbr   = (const int*)d_in[8];

    char* ws = (char*)d_ws;
    unsigned short* P   = (unsigned short*)ws;                          // 61,440,000 B
    unsigned short* Wp1 = (unsigned short*)(ws + 61440000);             // 524,288 B
    unsigned short* Wp3 = (unsigned short*)(ws + 61440000 + 524288);    // 131,072 B
    float* outp = (float*)d_out;

    hipLaunchKernelGGL(pack_weights, dim3(1280), dim3(256), 0, stream, fc_w, Wp1, Wp3);
    hipLaunchKernelGGL(gemm_p, dim3(235, 2), dim3(512), 0, stream, atom, fc_b, Wp1, P);
    hipLaunchKernelGGL(fused_conv, dim3(3750), dim3(512), 0, stream,
                       atom, bond, nbr, P, Wp3, ln1_g, ln1_b, ln2_g, ln2_b, outp);
}

// Round 13
// 273.628 us; speedup vs baseline: 1.0460x; 1.0460x over previous
//
#include <hip/hip_runtime.h>
#include <hip/hip_bf16.h>

#define N_ATOMS 30000
#define M_NBR   12

typedef __bf16 bf16x8 __attribute__((ext_vector_type(8)));
typedef float  f32x4  __attribute__((ext_vector_type(4)));

__device__ __forceinline__ unsigned pkbf(float a, float b) {
    union { __bf16 h[2]; unsigned u; } r;
    r.h[0] = (__bf16)a; r.h[1] = (__bf16)b;
    return r.u;
}
__device__ __forceinline__ unsigned short f2bf(float f) {
    union { __bf16 h; unsigned short s; } r; r.h = (__bf16)f; return r.s;
}
__device__ __forceinline__ float bflo(unsigned u) { union { unsigned x; float f; } v; v.x = u << 16;          return v.f; }
__device__ __forceinline__ float bfhi(unsigned u) { union { unsigned x; float f; } v; v.x = u & 0xffff0000u;  return v.f; }

__device__ __forceinline__ float fexp2(float x) { return __builtin_amdgcn_exp2f(x); }
__device__ __forceinline__ float flog2(float x) { return __builtin_amdgcn_logf(x); }

__device__ __forceinline__ float rowsum16(float x) {
    union { float f; int i; } a, b;
    a.f = x;
    b.i = __builtin_amdgcn_update_dpp(0, a.i, 0x121, 0xF, 0xF, true); a.f += b.f; // row_ror:1
    b.i = __builtin_amdgcn_update_dpp(0, a.i, 0x122, 0xF, 0xF, true); a.f += b.f; // row_ror:2
    b.i = __builtin_amdgcn_update_dpp(0, a.i, 0x124, 0xF, 0xF, true); a.f += b.f; // row_ror:4
    b.i = __builtin_amdgcn_update_dpp(0, a.i, 0x128, 0xF, 0xF, true); a.f += b.f; // row_ror:8
    return a.f;
}

// packed per-row address for z-column c (0..511): [band:8][l15:16][slot:4]
__device__ __forceinline__ int packAddr8(int c) {
    int cc = c & 255;
    int slot = ((cc >> 4) & 1) + ((c >> 8) << 1);
    return (cc >> 5) * 64 + (cc & 15) * 4 + slot;
}

// ---------------- Kernel 0: pack fc_w into bf16 fragment-order tables ----------
__global__ void pack_weights(const float* __restrict__ fc_w,
                             unsigned short* __restrict__ Wp1,
                             unsigned short* __restrict__ Wp3) {
    int idx = blockIdx.x * 256 + threadIdx.x;
    const int n1 = 32 * 1024 * 8;
    if (idx < n1) {
        int j = idx & 7, n = (idx >> 3) & 1023, g = idx >> 13;
        float v = (n < 512) ? fc_w[n * 640 + g * 8 + j]
                            : fc_w[(n - 512) * 640 + 256 + g * 8 + j];
        Wp1[idx] = f2bf(v);
    } else {
        int k = idx - n1;
        if (k < 16 * 512 * 8) {
            int j = k & 7, n = (k >> 3) & 511, g = k >> 12;
            Wp3[k] = f2bf(fc_w[n * 640 + 512 + g * 8 + j]);
        }
    }
}

// ---------------- Kernel 1: P1 = W1*atom + b, P2 = W2*atom, stored PACKED (bf16) ---
__global__ __launch_bounds__(512, 2) void gemm_p(
    const float* __restrict__ atom, const float* __restrict__ fc_b,
    const unsigned short* __restrict__ Wp1, unsigned short* __restrict__ P)
{
    __shared__ unsigned short sA[128 * 256];
    const int tid = threadIdx.x;
    const int r0 = blockIdx.x * 128;
    const int cb = blockIdx.y;

    #pragma unroll
    for (int s = 0; s < 8; ++s) {
        int G = tid + s * 512;
        int row = G >> 5, gc = G & 31;
        int grow = r0 + row;
        uint4 pk;
        if (grow < N_ATOMS) {
            const float4* src = reinterpret_cast<const float4*>(atom + (size_t)grow * 256 + gc * 8);
            float4 v0 = src[0], v1 = src[1];
            pk.x = pkbf(v0.x, v0.y); pk.y = pkbf(v0.z, v0.w);
            pk.z = pkbf(v1.x, v1.y); pk.w = pkbf(v1.z, v1.w);
        } else {
            pk = make_uint4(0u, 0u, 0u, 0u);
        }
        *reinterpret_cast<uint4*>(&sA[row * 256 + ((gc ^ (row & 7)) << 3)]) = pk;
    }
    __syncthreads();

    const int lane = tid & 63, wave = tid >> 6;
    const int wr = wave >> 2, wcc = wave & 3;
    const int l15 = lane & 15, l16 = lane >> 4;

    f32x4 acc[4][8];
    #pragma unroll
    for (int mt = 0; mt < 4; ++mt)
        #pragma unroll
        for (int nt = 0; nt < 8; ++nt) acc[mt][nt] = f32x4{0.f, 0.f, 0.f, 0.f};

    #pragma unroll
    for (int ks = 0; ks < 8; ++ks) {
        bf16x8 af[4];
        #pragma unroll
        for (int mt = 0; mt < 4; ++mt) {
            int row = wr * 64 + mt * 16 + l15;
            int g = ks * 4 + l16;
            af[mt] = *reinterpret_cast<const bf16x8*>(&sA[row * 256 + ((g ^ (row & 7)) << 3)]);
        }
        bf16x8 bfr[8];
        #pragma unroll
        for (int nt = 0; nt < 8; ++nt) {
            int col = cb * 512 + wcc * 128 + nt * 16 + l15;
            bfr[nt] = *reinterpret_cast<const bf16x8*>(&Wp1[((size_t)(ks * 4 + l16) * 1024 + col) * 8]);
        }
        #pragma unroll
        for (int mt = 0; mt < 4; ++mt)
            #pragma unroll
            for (int nt = 0; nt < 8; ++nt)
                acc[mt][nt] = __builtin_amdgcn_mfma_f32_16x16x32_bf16(af[mt], bfr[nt], acc[mt][nt], 0, 0, 0);
    }

    #pragma unroll
    for (int np = 0; np < 4; ++np) {
        int zc0 = wcc * 128 + np * 32 + l15;
        float b0 = (cb == 0) ? fc_b[zc0] : 0.f;
        float b1 = (cb == 0) ? fc_b[zc0 + 16] : 0.f;
        int pa = cb * 512 + packAddr8(zc0);
        #pragma unroll
        for (int mt = 0; mt < 4; ++mt) {
            #pragma unroll
            for (int j = 0; j < 4; ++j) {
                int row = r0 + wr * 64 + mt * 16 + l16 * 4 + j;
                if (row < N_ATOMS)
                    *reinterpret_cast<unsigned*>(&P[(size_t)row * 1024 + pa]) =
                        pkbf(acc[mt][2 * np][j] + b0, acc[mt][2 * np + 1][j] + b1);
            }
        }
    }
}

// ================= Kernel 2 helpers =================
__device__ __forceinline__ void bondLoad(const float* __restrict__ bond, int i0, int tid, float4 bv[3]) {
    #pragma unroll
    for (int s = 0; s < 3; ++s) {
        int g = tid + s * 512;                    // 1536 8B-out granules, exact
        int row = g >> 5, gc = g & 31;
        bv[s] = *reinterpret_cast<const float4*>(bond + (size_t)(i0 * 12 + row) * 128 + gc * 4);
    }
}
__device__ __forceinline__ void bondWrite(const float4 bv[3], int tid, unsigned short* sAbuf) {
    #pragma unroll
    for (int s = 0; s < 3; ++s) {
        int g = tid + s * 512;
        int row = g >> 5, gc = g & 31;
        uint2 pk;
        pk.x = pkbf(bv[s].x, bv[s].y); pk.y = pkbf(bv[s].z, bv[s].w);
        int elem = (((gc >> 1) ^ (row & 7)) << 3) + ((gc & 1) << 2);
        *reinterpret_cast<uint2*>(&sAbuf[row * 128 + elem]) = pk;
    }
}
__device__ __forceinline__ void loadP(const char* __restrict__ Pb, const int* __restrict__ nbr,
                                      int i0, int l16, unsigned cOff, uint2 p2q[12], uint2 p1q[3]) {
    int4 nbq0 = *reinterpret_cast<const int4*>(&nbr[i0 * 12 +      l16 * 4]);
    int4 nbq1 = *reinterpret_cast<const int4*>(&nbr[i0 * 12 + 16 + l16 * 4]);
    int4 nbq2 = *reinterpret_cast<const int4*>(&nbr[i0 * 12 + 32 + l16 * 4]);
    const int* n0 = reinterpret_cast<const int*>(&nbq0);
    const int* n1 = reinterpret_cast<const int*>(&nbq1);
    const int* n2 = reinterpret_cast<const int*>(&nbq2);
    #pragma unroll
    for (int j = 0; j < 4; ++j) {
        p2q[j]     = *reinterpret_cast<const uint2*>(Pb + ((unsigned)n0[j] * 2048u + 1024u + cOff));
        p2q[4 + j] = *reinterpret_cast<const uint2*>(Pb + ((unsigned)n1[j] * 2048u + 1024u + cOff));
        p2q[8 + j] = *reinterpret_cast<const uint2*>(Pb + ((unsigned)n2[j] * 2048u + 1024u + cOff));
    }
    #pragma unroll
    for (int mt = 0; mt < 3; ++mt) {
        unsigned li = (unsigned)((mt * 16 + l16 * 4) / 12);
        p1q[mt] = *reinterpret_cast<const uint2*>(Pb + (((unsigned)i0 + li) * 2048u + cOff));
    }
}
__device__ __forceinline__ void accInit(const uint2 p2q[12], const uint2 p1q[3], f32x4 acc[3][4]) {
    #pragma unroll
    for (int mt = 0; mt < 3; ++mt) {
        uint2 c1 = p1q[mt];
        float p1v[4] = { bflo(c1.x), bfhi(c1.x), bflo(c1.y), bfhi(c1.y) };
        #pragma unroll
        for (int j = 0; j < 4; ++j) {
            uint2 c2 = p2q[mt * 4 + j];
            acc[mt][0][j] = p1v[0] + bflo(c2.x);
            acc[mt][1][j] = p1v[1] + bfhi(c2.x);
            acc[mt][2][j] = p1v[2] + bflo(c2.y);
            acc[mt][3][j] = p1v[3] + bfhi(c2.y);
        }
    }
}
__device__ __forceinline__ void gemmTile(const unsigned short* __restrict__ sAbuf,
                                         const unsigned short* __restrict__ Wp3,
                                         int l15, int l16, int wc, f32x4 acc[3][4]) {
    #pragma unroll
    for (int ks = 0; ks < 4; ++ks) {
        #pragma unroll
        for (int p = 0; p < 2; ++p) {
            bf16x8 b0 = *reinterpret_cast<const bf16x8*>(
                &Wp3[((size_t)(ks * 4 + l16) * 512 + p * 256 + wc * 32 + l15) * 8]);
            bf16x8 b1 = *reinterpret_cast<const bf16x8*>(
                &Wp3[((size_t)(ks * 4 + l16) * 512 + p * 256 + wc * 32 + 16 + l15) * 8]);
            #pragma unroll
            for (int mt = 0; mt < 3; ++mt) {
                int row = mt * 16 + l15;
                bf16x8 af = *reinterpret_cast<const bf16x8*>(
                    &sAbuf[row * 128 + (((ks * 4 + l16) ^ (row & 7)) << 3)]);
                acc[mt][2 * p]     = __builtin_amdgcn_mfma_f32_16x16x32_bf16(af, b0, acc[mt][2 * p], 0, 0, 0);
                acc[mt][2 * p + 1] = __builtin_amdgcn_mfma_f32_16x16x32_bf16(af, b1, acc[mt][2 * p + 1], 0, 0, 0);
            }
        }
    }
}
__device__ __forceinline__ void pass1Stats(const f32x4 acc[3][4], float (*sRed)[48][9],
                                           int l16, int l15, int wc) {
    #pragma unroll
    for (int mt = 0; mt < 3; ++mt) {
        #pragma unroll
        for (int j = 0; j < 4; ++j) {
            const int row = mt * 16 + l16 * 4 + j;
            float z0 = acc[mt][0][j], z1 = acc[mt][1][j];
            float z2 = acc[mt][2][j], z3 = acc[mt][3][j];
            float s = (z0 + z1) + (z2 + z3);
            float q = fmaf(z0, z0, fmaf(z1, z1, fmaf(z2, z2, z3 * z3)));
            s = rowsum16(s);
            q = rowsum16(q);
            if (l15 == 0) { sRed[0][row][wc] = s; sRed[1][row][wc] = q; }
        }
    }
}
__device__ __forceinline__ void miniReduce(int tid, float (*sRed)[48][9], float2* sStat, float L2E) {
    if (tid < 48) {
        float s4 = 0.f, q4 = 0.f;
        #pragma unroll
        for (int w = 0; w < 8; ++w) { s4 += sRed[0][tid][w]; q4 += sRed[1][tid][w]; }
        float mu = s4 * (1.f / 512.f);
        float var = q4 * (1.f / 512.f) - mu * mu;
        float rs = __builtin_amdgcn_rsqf(var + 1e-5f) * L2E;
        sStat[tid] = make_float2(rs, mu * rs);
    }
}
__device__ __forceinline__ void pass2(const f32x4 acc[3][4], const float2* sStat,
                                      const float g1[2], const float gC[2],
                                      const float l2b1[2], const float l2bC[2],
                                      float (*sObuf)[256], int l16, int l15, int wc) {
    #pragma unroll
    for (int mt = 0; mt < 3; ++mt) {
        const int li = (mt * 16 + l16 * 4) / 12;
        float2 st[4];
        #pragma unroll
        for (int j = 0; j < 4; ++j) st[j] = sStat[mt * 16 + l16 * 4 + j];
        #pragma unroll
        for (int nt = 0; nt < 2; ++nt) {
            float tq = 0.f;
            #pragma unroll
            for (int j = 0; j < 4; ++j) {
                float ug = fmaf(fmaf(acc[mt][nt][j],     st[j].x, -st[j].y), g1[nt], l2b1[nt]);
                float uc = fmaf(fmaf(acc[mt][nt + 2][j], st[j].x, -st[j].y), gC[nt], l2bC[nt]);
                float gt  = __builtin_amdgcn_rcpf(1.f + fexp2(-ug));
                float sp2 = flog2(1.f + fexp2(uc));
                tq = fmaf(gt, sp2, tq);
            }
            atomicAdd(&sObuf[li][wc * 32 + nt * 16 + l15], tq);
        }
    }
}
__device__ __forceinline__ void ln2Out(const float (*sObuf)[256], int i0, int wc, int lane,
                                       const float* __restrict__ atom,
                                       const float* __restrict__ ln2_g, const float* __restrict__ ln2_b,
                                       float* __restrict__ out) {
    if (wc < 4) {
        const int gi = i0 + wc;
        float v[4]; float s = 0.f, q = 0.f;
        #pragma unroll
        for (int qd = 0; qd < 4; ++qd) {
            v[qd] = sObuf[wc][lane + qd * 64];
            s += v[qd]; q = fmaf(v[qd], v[qd], q);
        }
        #pragma unroll
        for (int msk = 1; msk <= 32; msk <<= 1) {
            s += __shfl_xor(s, msk, 64);
            q += __shfl_xor(q, msk, 64);
        }
        float mu = s * (1.f / 256.f);
        float var = q * (1.f / 256.f) - mu * mu;
        float rstd = __builtin_amdgcn_rsqf(var + 1e-5f);
        #pragma unroll
        for (int qd = 0; qd < 4; ++qd) {
            int a = lane + qd * 64;
            out[(size_t)gi * 256 + a] = atom[(size_t)gi * 256 + a]
                                      + (v[qd] - mu) * rstd * ln2_g[a] + ln2_b[a];
        }
    }
}

// ---------------- Kernel 2: two software-pipelined tiles (8 atoms) per block --------------
// Register choreography: tile1's P gathers (30 regs) fly over tile0's epilogue; tile1's bond
// loads (24 regs) issue only AFTER accInit(t1) frees the P regs. Peak stays < 128 unified.
__global__ __launch_bounds__(512, 4) void fused_conv(
    const float* __restrict__ atom, const float* __restrict__ bond,
    const int* __restrict__ nbr, const unsigned short* __restrict__ P,
    const unsigned short* __restrict__ Wp3,
    const float* __restrict__ ln1_g, const float* __restrict__ ln1_b,
    const float* __restrict__ ln2_g, const float* __restrict__ ln2_b,
    float* __restrict__ out)
{
    __shared__ unsigned short sA[2][48 * 128];   // 24KB double-buffered bond tiles
    __shared__ float sRed[2][48][9];
    __shared__ float2 sStat[48];
    __shared__ float sO[2][4][256];              // 8KB double-buffered mean accumulators

    const int tid = threadIdx.x;
    const int i00 = blockIdx.x * 8;              // 3750 blocks, 2 tiles of 4 atoms each
    const int i01 = i00 + 4;
    const int lane = tid & 63, wc = tid >> 6;
    const int l15 = lane & 15, l16 = lane >> 4;
    const float L2E = 1.4426950408889634f;
    const char* Pb = reinterpret_cast<const char*>(P);
    const unsigned cOff = (unsigned)(wc * 128 + l15 * 8);

    {   // zero both sO buffers
        float* so = &sO[0][0][0];
        so[tid] = 0.f; so[tid + 512] = 0.f; so[tid + 1024] = 0.f; so[tid + 1536] = 0.f;
    }

    // ---- tile0 prologue ----
    float4 bv[3];
    bondLoad(bond, i00, tid, bv);                // HBM: issue first
    uint2 p2q[12], p1q[3];
    loadP(Pb, nbr, i00, l16, cOff, p2q, p1q);    // nbr -> gathers, in flight with bond
    bondWrite(bv, tid, sA[0]);                   // waits on bond only; bv dies
    f32x4 acc[3][4];
    accInit(p2q, p1q, acc);                      // waits gathers; p regs die
    __syncthreads();                             // B1: sA[0] ready
    gemmTile(sA[0], Wp3, l15, l16, wc, acc);

    // ---- tile1 P gathers: issued here, consumed after pass2(t0) (~2000cy later) ----
    loadP(Pb, nbr, i01, l16, cOff, p2q, p1q);    // reuse arrays; 30 regs in flight

    // ---- tile0 epilogue ----
    pass1Stats(acc, sRed, l16, l15, wc);
    float g1[2], gC[2], l2b1[2], l2bC[2];        // LN1 params: shared by both tiles
    #pragma unroll
    for (int nt = 0; nt < 2; ++nt) {
        int a = wc * 32 + nt * 16 + l15;
        g1[nt] = ln1_g[a];       l2b1[nt] = ln1_b[a] * L2E;
        gC[nt] = ln1_g[256 + a]; l2bC[nt] = ln1_b[256 + a] * L2E;
    }
    __syncthreads();                             // B2: sRed(t0) done
    miniReduce(tid, sRed, sStat, L2E);
    __syncthreads();                             // B3
    pass2(acc, sStat, g1, gC, l2b1, l2bC, sO[0], l16, l15, wc);   // acc(t0) dies
    accInit(p2q, p1q, acc);                      // acc -> tile1; P regs die
    bondLoad(bond, i01, tid, bv);                // 24 regs; latency hides under B4+ln2Out
    __syncthreads();                             // B4: sO[0] atomics done
    ln2Out(sO[0], i00, wc, lane, atom, ln2_g, ln2_b, out);
    bondWrite(bv, tid, sA[1]);                   // waits bond(t1); bv dies
    __syncthreads();                             // B5: sA[1] ready
    // ---- tile1 compute ----
    gemmTile(sA[1], Wp3, l15, l16, wc, acc);
    pass1Stats(acc, sRed, l16, l15, wc);
    __syncthreads();                             // B6
    miniReduce(tid, sRed, sStat, L2E);
    __syncthreads();                             // B7
    pass2(acc, sStat, g1, gC, l2b1, l2bC, sO[1], l16, l15, wc);
    __syncthreads();                             // B8
    ln2Out(sO[1], i01, wc, lane, atom, ln2_g, ln2_b, out);
}

extern "C" void kernel_launch(void* const* d_in, const int* in_sizes, int n_in,
                              void* d_out, int out_size, void* d_ws, size_t ws_size,
                              hipStream_t stream) {
    const float* atom  = (const float*)d_in[0];
    const float* bond  = (const float*)d_in[1];
    const float* fc_w  = (const float*)d_in[2];
    const float* fc_b  = (const float*)d_in[3];
    const float* ln1_g = (const float*)d_in[4];
    const float* ln1_b = (const float*)d_in[5];
    const float* ln2_g = (const float*)d_in[6];
    const float* ln2_b = (const float*)d_in[7];
    const int*   nbr   = (const int*)d_in[8];

    char* ws = (char*)d_ws;
    unsigned short* P   = (unsigned short*)ws;                          // 61,440,000 B
    unsigned short* Wp1 = (unsigned short*)(ws + 61440000);             // 524,288 B
    unsigned short* Wp3 = (unsigned short*)(ws + 61440000 + 524288);    // 131,072 B
    float* outp = (float*)d_out;

    hipLaunchKernelGGL(pack_weights, dim3(1280), dim3(256), 0, stream, fc_w, Wp1, Wp3);
    hipLaunchKernelGGL(gemm_p, dim3(235, 2), dim3(512), 0, stream, atom, fc_b, Wp1, P);
    hipLaunchKernelGGL(fused_conv, dim3(3750), dim3(512), 0, stream,
                       atom, bond, nbr, P, Wp3, ln1_g, ln1_b, ln2_g, ln2_b, outp);
}

// Round 14
// 239.678 us; speedup vs baseline: 1.1941x; 1.1417x over previous
//
#include <hip/hip_runtime.h>
#include <hip/hip_bf16.h>

#define N_ATOMS 30000
#define M_NBR   12

typedef __bf16 bf16x8 __attribute__((ext_vector_type(8)));
typedef float  f32x4  __attribute__((ext_vector_type(4)));

__device__ __forceinline__ unsigned pkbf(float a, float b) {
    union { __bf16 h[2]; unsigned u; } r;
    r.h[0] = (__bf16)a; r.h[1] = (__bf16)b;
    return r.u;
}
__device__ __forceinline__ unsigned short f2bf(float f) {
    union { __bf16 h; unsigned short s; } r; r.h = (__bf16)f; return r.s;
}
__device__ __forceinline__ float bflo(unsigned u) { union { unsigned x; float f; } v; v.x = u << 16;          return v.f; }
__device__ __forceinline__ float bfhi(unsigned u) { union { unsigned x; float f; } v; v.x = u & 0xffff0000u;  return v.f; }

__device__ __forceinline__ float fexp2(float x) { return __builtin_amdgcn_exp2f(x); }
__device__ __forceinline__ float flog2(float x) { return __builtin_amdgcn_logf(x); }

__device__ __forceinline__ float rowsum16(float x) {
    union { float f; int i; } a, b;
    a.f = x;
    b.i = __builtin_amdgcn_update_dpp(0, a.i, 0x121, 0xF, 0xF, true); a.f += b.f; // row_ror:1
    b.i = __builtin_amdgcn_update_dpp(0, a.i, 0x122, 0xF, 0xF, true); a.f += b.f; // row_ror:2
    b.i = __builtin_amdgcn_update_dpp(0, a.i, 0x124, 0xF, 0xF, true); a.f += b.f; // row_ror:4
    b.i = __builtin_amdgcn_update_dpp(0, a.i, 0x128, 0xF, 0xF, true); a.f += b.f; // row_ror:8
    return a.f;
}

// packed per-row address for z-column c (0..511): [band:8][l15:16][slot:4]
// band=(c&255)>>5, slot = bit4(c&255) + 2*(c>=256)
__device__ __forceinline__ int packAddr8(int c) {
    int cc = c & 255;
    int slot = ((cc >> 4) & 1) + ((c >> 8) << 1);
    return (cc >> 5) * 64 + (cc & 15) * 4 + slot;
}

// ---------------- Kernel 0: pack fc_w into bf16 fragment-order tables ----------
__global__ void pack_weights(const float* __restrict__ fc_w,
                             unsigned short* __restrict__ Wp1,
                             unsigned short* __restrict__ Wp3) {
    int idx = blockIdx.x * 256 + threadIdx.x;
    const int n1 = 32 * 1024 * 8;
    if (idx < n1) {
        int j = idx & 7, n = (idx >> 3) & 1023, g = idx >> 13;
        float v = (n < 512) ? fc_w[n * 640 + g * 8 + j]
                            : fc_w[(n - 512) * 640 + 256 + g * 8 + j];
        Wp1[idx] = f2bf(v);
    } else {
        int k = idx - n1;
        if (k < 16 * 512 * 8) {
            int j = k & 7, n = (k >> 3) & 511, g = k >> 12;
            Wp3[k] = f2bf(fc_w[n * 640 + 512 + g * 8 + j]);
        }
    }
}

// ---------------- Kernel 1: P1 = W1*atom + b, P2 = W2*atom, stored PACKED (bf16) ---
__global__ __launch_bounds__(512, 2) void gemm_p(
    const float* __restrict__ atom, const float* __restrict__ fc_b,
    const unsigned short* __restrict__ Wp1, unsigned short* __restrict__ P)
{
    __shared__ unsigned short sA[128 * 256];
    const int tid = threadIdx.x;
    const int r0 = blockIdx.x * 128;
    const int cb = blockIdx.y;

    #pragma unroll
    for (int s = 0; s < 8; ++s) {
        int G = tid + s * 512;
        int row = G >> 5, gc = G & 31;
        int grow = r0 + row;
        uint4 pk;
        if (grow < N_ATOMS) {
            const float4* src = reinterpret_cast<const float4*>(atom + (size_t)grow * 256 + gc * 8);
            float4 v0 = src[0], v1 = src[1];
            pk.x = pkbf(v0.x, v0.y); pk.y = pkbf(v0.z, v0.w);
            pk.z = pkbf(v1.x, v1.y); pk.w = pkbf(v1.z, v1.w);
        } else {
            pk = make_uint4(0u, 0u, 0u, 0u);
        }
        *reinterpret_cast<uint4*>(&sA[row * 256 + ((gc ^ (row & 7)) << 3)]) = pk;
    }
    __syncthreads();

    const int lane = tid & 63, wave = tid >> 6;
    const int wr = wave >> 2, wcc = wave & 3;
    const int l15 = lane & 15, l16 = lane >> 4;

    f32x4 acc[4][8];
    #pragma unroll
    for (int mt = 0; mt < 4; ++mt)
        #pragma unroll
        for (int nt = 0; nt < 8; ++nt) acc[mt][nt] = f32x4{0.f, 0.f, 0.f, 0.f};

    #pragma unroll
    for (int ks = 0; ks < 8; ++ks) {
        bf16x8 af[4];
        #pragma unroll
        for (int mt = 0; mt < 4; ++mt) {
            int row = wr * 64 + mt * 16 + l15;
            int g = ks * 4 + l16;
            af[mt] = *reinterpret_cast<const bf16x8*>(&sA[row * 256 + ((g ^ (row & 7)) << 3)]);
        }
        bf16x8 bfr[8];
        #pragma unroll
        for (int nt = 0; nt < 8; ++nt) {
            int col = cb * 512 + wcc * 128 + nt * 16 + l15;
            bfr[nt] = *reinterpret_cast<const bf16x8*>(&Wp1[((size_t)(ks * 4 + l16) * 1024 + col) * 8]);
        }
        #pragma unroll
        for (int mt = 0; mt < 4; ++mt)
            #pragma unroll
            for (int nt = 0; nt < 8; ++nt)
                acc[mt][nt] = __builtin_amdgcn_mfma_f32_16x16x32_bf16(af[mt], bfr[nt], acc[mt][nt], 0, 0, 0);
    }

    #pragma unroll
    for (int np = 0; np < 4; ++np) {
        int zc0 = wcc * 128 + np * 32 + l15;
        float b0 = (cb == 0) ? fc_b[zc0] : 0.f;
        float b1 = (cb == 0) ? fc_b[zc0 + 16] : 0.f;
        int pa = cb * 512 + packAddr8(zc0);
        #pragma unroll
        for (int mt = 0; mt < 4; ++mt) {
            #pragma unroll
            for (int j = 0; j < 4; ++j) {
                int row = r0 + wr * 64 + mt * 16 + l16 * 4 + j;
                if (row < N_ATOMS)
                    *reinterpret_cast<unsigned*>(&P[(size_t)row * 1024 + pa]) =
                        pkbf(acc[mt][2 * np][j] + b0, acc[mt][2 * np + 1][j] + b1);
            }
        }
    }
}

// ---------------- Kernel 2: 256 threads / 4 waves / 2 atoms per block --------------
// Rows 0..23 real (2 atoms x 12), 24..31 zero-padded. Wave wc owns 64 gate + 64 core cols.
// acc[2][8] = 64 regs -> 4 blocks/CU co-resident = 4 independent barrier streams.
// 3 barriers total: B1 (LDS staged), B2 (LN1 partials), B3 (LN2 partials).
__global__ __launch_bounds__(256, 4) void fused_conv(
    const float* __restrict__ atom, const float* __restrict__ bond,
    const int* __restrict__ nbr, const unsigned short* __restrict__ P,
    const unsigned short* __restrict__ Wp3,
    const float* __restrict__ ln1_g, const float* __restrict__ ln1_b,
    const float* __restrict__ ln2_g, const float* __restrict__ ln2_b,
    float* __restrict__ out)
{
    __shared__ unsigned short sA[32 * 128];             // 8KB bond tile (bf16, swizzled)
    __shared__ __align__(16) float sRed[2][32][4];      // LN1 wave partials
    __shared__ __align__(16) float sL2[2][2][4];        // [atom][s|q][wave] LN2 partials

    const int tid = threadIdx.x;
    const int i0 = blockIdx.x * 2;                      // 15000 blocks exact
    const int lane = tid & 63, wc = tid >> 6;           // wc 0..3
    const int l15 = lane & 15, l16 = lane >> 4;
    const float L2E = 1.4426950408889634f;
    const char* Pb = reinterpret_cast<const char*>(P);
    const unsigned cOffA = (unsigned)(wc * 256 + l15 * 8);   // band 2wc
    const unsigned cOffB = cOffA + 128u;                     // band 2wc+1

    // ---- 1) bond loads (24 real rows): 768 granules of 4 floats, 3/thread ----
    float4 bv[3];
    #pragma unroll
    for (int s = 0; s < 3; ++s) {
        int g = tid + s * 256;
        int row = g >> 5, gc = g & 31;
        bv[s] = *reinterpret_cast<const float4*>(bond + (size_t)(i0 * 12 + row) * 128 + gc * 4);
    }

    // ---- 2) nbr + P2/P1 gathers (rows: mt0 = l16*4+j; mt1 = 16+l16*4+j, real only l16<2) ----
    int4 nbq0 = *reinterpret_cast<const int4*>(&nbr[i0 * 12 + l16 * 4]);
    int off16 = (l16 < 2) ? (16 + l16 * 4) : 20;        // clamped, always in-bounds
    int4 nbq1 = *reinterpret_cast<const int4*>(&nbr[i0 * 12 + off16]);

    uint2 p2q[2][4][2];
    {
        const int* n0 = reinterpret_cast<const int*>(&nbq0);
        const int* n1 = reinterpret_cast<const int*>(&nbq1);
        #pragma unroll
        for (int j = 0; j < 4; ++j) {
            unsigned b0 = (unsigned)n0[j] * 2048u + 1024u;
            p2q[0][j][0] = *reinterpret_cast<const uint2*>(Pb + b0 + cOffA);
            p2q[0][j][1] = *reinterpret_cast<const uint2*>(Pb + b0 + cOffB);
            unsigned b1 = (unsigned)n1[j] * 2048u + 1024u;
            p2q[1][j][0] = *reinterpret_cast<const uint2*>(Pb + b1 + cOffA);
            p2q[1][j][1] = *reinterpret_cast<const uint2*>(Pb + b1 + cOffB);
        }
    }
    uint2 p1q[2][2];
    {
        unsigned a0 = (unsigned)(i0 + ((l16 < 3) ? 0 : 1)) * 2048u;   // mt0 atom
        p1q[0][0] = *reinterpret_cast<const uint2*>(Pb + a0 + cOffA);
        p1q[0][1] = *reinterpret_cast<const uint2*>(Pb + a0 + cOffB);
        unsigned a1 = (unsigned)(i0 + 1) * 2048u;                     // mt1 atom (real rows)
        p1q[1][0] = *reinterpret_cast<const uint2*>(Pb + a1 + cOffA);
        p1q[1][1] = *reinterpret_cast<const uint2*>(Pb + a1 + cOffB);
    }

    // ---- 3) stage bond -> LDS (waits bond only); zero pad rows 24..31 ----
    #pragma unroll
    for (int s = 0; s < 3; ++s) {
        int g = tid + s * 256;
        int row = g >> 5, gc = g & 31;
        uint2 pk;
        pk.x = pkbf(bv[s].x, bv[s].y); pk.y = pkbf(bv[s].z, bv[s].w);
        int elem = (((gc >> 1) ^ (row & 7)) << 3) + ((gc & 1) << 2);
        *reinterpret_cast<uint2*>(&sA[row * 128 + elem]) = pk;
    }
    {
        int row = 24 + (tid >> 5), gc = tid & 31;
        *reinterpret_cast<uint2*>(&sA[row * 128 + gc * 4]) = make_uint2(0u, 0u);
    }

    // ---- 4) acc := P1 + P2 (waits gathers; gather regs die before GEMM) ----
    // acc[mt][nt]: nt = p*4 + np*2 + b16 ; cols = p*256 + wc*64 + np*32 + b16*16 + l15
    f32x4 acc[2][8];
    #pragma unroll
    for (int mt = 0; mt < 2; ++mt)
        #pragma unroll
        for (int np = 0; np < 2; ++np) {
            uint2 c1 = p1q[mt][np];
            float pg0 = bflo(c1.x), pg1 = bfhi(c1.x);
            float pc0 = bflo(c1.y), pc1 = bfhi(c1.y);
            #pragma unroll
            for (int j = 0; j < 4; ++j) {
                uint2 c2 = p2q[mt][j][np];
                acc[mt][np * 2 + 0][j]     = pg0 + bflo(c2.x);
                acc[mt][np * 2 + 1][j]     = pg1 + bfhi(c2.x);
                acc[mt][4 + np * 2 + 0][j] = pc0 + bflo(c2.y);
                acc[mt][4 + np * 2 + 1][j] = pc1 + bfhi(c2.y);
            }
        }
    __syncthreads();                                    // B1: sA ready

    // ---- GEMM: acc += [32,128(bond)] @ Wp3 ----
    #pragma unroll
    for (int ks = 0; ks < 4; ++ks) {
        bf16x8 af[2];
        #pragma unroll
        for (int mt = 0; mt < 2; ++mt) {
            int row = mt * 16 + l15;
            af[mt] = *reinterpret_cast<const bf16x8*>(
                &sA[row * 128 + (((ks * 4 + l16) ^ (row & 7)) << 3)]);
        }
        #pragma unroll
        for (int p = 0; p < 2; ++p)
            #pragma unroll
            for (int np = 0; np < 2; ++np) {
                int colbase = p * 256 + wc * 64 + np * 32 + l15;
                bf16x8 b0 = *reinterpret_cast<const bf16x8*>(
                    &Wp3[((size_t)(ks * 4 + l16) * 512 + colbase) * 8]);
                bf16x8 b1 = *reinterpret_cast<const bf16x8*>(
                    &Wp3[((size_t)(ks * 4 + l16) * 512 + colbase + 16) * 8]);
                #pragma unroll
                for (int mt = 0; mt < 2; ++mt) {
                    acc[mt][p * 4 + np * 2 + 0] = __builtin_amdgcn_mfma_f32_16x16x32_bf16(
                        af[mt], b0, acc[mt][p * 4 + np * 2 + 0], 0, 0, 0);
                    acc[mt][p * 4 + np * 2 + 1] = __builtin_amdgcn_mfma_f32_16x16x32_bf16(
                        af[mt], b1, acc[mt][p * 4 + np * 2 + 1], 0, 0, 0);
                }
            }
    }

    // ---- pass 1: LN1 partial stats per row (pads produce unused garbage) ----
    #pragma unroll
    for (int mt = 0; mt < 2; ++mt)
        #pragma unroll
        for (int j = 0; j < 4; ++j) {
            int row = mt * 16 + l16 * 4 + j;
            float s = 0.f, q = 0.f;
            #pragma unroll
            for (int nt = 0; nt < 8; ++nt) {
                float z = acc[mt][nt][j];
                s += z; q = fmaf(z, z, q);
            }
            s = rowsum16(s);
            q = rowsum16(q);
            if (l15 == 0) { sRed[0][row][wc] = s; sRed[1][row][wc] = q; }
        }

    // LN1 affine params (log2e-folded biases); latency hides under barrier
    float g1[4], gC[4], l2b1[4], l2bC[4];
    #pragma unroll
    for (int np = 0; np < 2; ++np)
        #pragma unroll
        for (int b = 0; b < 2; ++b) {
            int nt = np * 2 + b;
            int a = wc * 64 + np * 32 + b * 16 + l15;
            g1[nt] = ln1_g[a];       l2b1[nt] = ln1_b[a] * L2E;
            gC[nt] = ln1_g[256 + a]; l2bC[nt] = ln1_b[256 + a] * L2E;
        }
    __syncthreads();                                    // B2: sRed ready

    // ---- pass 2: per-thread stats fold + sigmoid*softplus + l16-butterfly mean ----
    float pa0[4] = {0.f, 0.f, 0.f, 0.f};
    float pa1[4] = {0.f, 0.f, 0.f, 0.f};
    #pragma unroll
    for (int mt = 0; mt < 2; ++mt) {
        float rs[4], mr[4];
        #pragma unroll
        for (int j = 0; j < 4; ++j) {
            int row = mt * 16 + l16 * 4 + j;
            float4 s4 = *reinterpret_cast<const float4*>(&sRed[0][row][0]);
            float4 q4 = *reinterpret_cast<const float4*>(&sRed[1][row][0]);
            float ssum = (s4.x + s4.y) + (s4.z + s4.w);
            float qsum = (q4.x + q4.y) + (q4.z + q4.w);
            float mu = ssum * (1.f / 512.f);
            float var = qsum * (1.f / 512.f) - mu * mu;
            float r = __builtin_amdgcn_rsqf(var + 1e-5f) * L2E;
            rs[j] = r; mr[j] = mu * r;
        }
        #pragma unroll
        for (int nt = 0; nt < 4; ++nt) {
            float tq = 0.f;
            #pragma unroll
            for (int j = 0; j < 4; ++j) {
                float ug = fmaf(fmaf(acc[mt][nt][j],     rs[j], -mr[j]), g1[nt], l2b1[nt]);
                float uc = fmaf(fmaf(acc[mt][nt + 4][j], rs[j], -mr[j]), gC[nt], l2bC[nt]);
                float gt  = __builtin_amdgcn_rcpf(1.f + fexp2(-ug));
                float sp2 = flog2(1.f + fexp2(uc));
                tq = fmaf(gt, sp2, tq);
            }
            if (mt == 0) {
                if (l16 < 3) pa0[nt] += tq; else pa1[nt] += tq;
            } else {
                if (l16 < 2) pa1[nt] += tq;
            }
        }
    }
    #pragma unroll
    for (int nt = 0; nt < 4; ++nt) {                    // sum the 3 contributors across l16
        pa0[nt] += __shfl_xor(pa0[nt], 16, 64);
        pa0[nt] += __shfl_xor(pa0[nt], 32, 64);
        pa1[nt] += __shfl_xor(pa1[nt], 16, 64);
        pa1[nt] += __shfl_xor(pa1[nt], 32, 64);
    }

    // ---- LN2 partials over this wave's 64 output cols (scale-invariant: no /12, no ln2) ----
    {
        float s0 = (pa0[0] + pa0[1]) + (pa0[2] + pa0[3]);
        float q0 = fmaf(pa0[0], pa0[0], fmaf(pa0[1], pa0[1], fmaf(pa0[2], pa0[2], pa0[3] * pa0[3])));
        float s1 = (pa1[0] + pa1[1]) + (pa1[2] + pa1[3]);
        float q1 = fmaf(pa1[0], pa1[0], fmaf(pa1[1], pa1[1], fmaf(pa1[2], pa1[2], pa1[3] * pa1[3])));
        s0 = rowsum16(s0); q0 = rowsum16(q0);
        s1 = rowsum16(s1); q1 = rowsum16(q1);
        if (lane == 0) {
            sL2[0][0][wc] = s0; sL2[0][1][wc] = q0;
            sL2[1][0][wc] = s1; sL2[1][1][wc] = q1;
        }
    }
    __syncthreads();                                    // B3: sL2 ready

    // ---- LN2 + residual: l16 group a (0,1) outputs atom a ----
    if (l16 < 2) {
        const int a = l16;
        const int gi = i0 + a;
        float4 sv = *reinterpret_cast<const float4*>(&sL2[a][0][0]);
        float4 qv = *reinterpret_cast<const float4*>(&sL2[a][1][0]);
        float ssum = (sv.x + sv.y) + (sv.z + sv.w);
        float qsum = (qv.x + qv.y) + (qv.z + qv.w);
        float mu = ssum * (1.f / 256.f);
        float var = qsum * (1.f / 256.f) - mu * mu;
        float rstd = __builtin_amdgcn_rsqf(var + 1e-5f);
        float vv[4];
        #pragma unroll
        for (int nt = 0; nt < 4; ++nt) vv[nt] = (l16 == 0) ? pa0[nt] : pa1[nt];
        #pragma unroll
        for (int np = 0; np < 2; ++np)
            #pragma unroll
            for (int b = 0; b < 2; ++b) {
                int nt = np * 2 + b;
                int c = wc * 64 + np * 32 + b * 16 + l15;
                out[(size_t)gi * 256 + c] = atom[(size_t)gi * 256 + c]
                                          + (vv[nt] - mu) * rstd * ln2_g[c] + ln2_b[c];
            }
    }
}

extern "C" void kernel_launch(void* const* d_in, const int* in_sizes, int n_in,
                              void* d_out, int out_size, void* d_ws, size_t ws_size,
                              hipStream_t stream) {
    const float* atom  = (const float*)d_in[0];
    const float* bond  = (const float*)d_in[1];
    const float* fc_w  = (const float*)d_in[2];
    const float* fc_b  = (const float*)d_in[3];
    const float* ln1_g = (const float*)d_in[4];
    const float* ln1_b = (const float*)d_in[5];
    const float* ln2_g = (const float*)d_in[6];
    const float* ln2_b = (const float*)d_in[7];
    const int*   nbr   = (const int*)d_in[8];

    char* ws = (char*)d_ws;
    unsigned short* P   = (unsigned short*)ws;                          // 61,440,000 B
    unsigned short* Wp1 = (unsigned short*)(ws + 61440000);             // 524,288 B
    unsigned short* Wp3 = (unsigned short*)(ws + 61440000 + 524288);    // 131,072 B
    float* outp = (float*)d_out;

    hipLaunchKernelGGL(pack_weights, dim3(1280), dim3(256), 0, stream, fc_w, Wp1, Wp3);
    hipLaunchKernelGGL(gemm_p, dim3(235, 2), dim3(512), 0, stream, atom, fc_b, Wp1, P);
    hipLaunchKernelGGL(fused_conv, dim3(15000), dim3(256), 0, stream,
                       atom, bond, nbr, P, Wp3, ln1_g, ln1_b, ln2_g, ln2_b, outp);
}